// Round 6
// baseline (353.644 us; speedup 1.0000x reference)
//
#include <hip/hip_runtime.h>
#include <hip/hip_bf16.h>
#include <math.h>

#define N_NODES 10000

typedef __attribute__((ext_vector_type(8))) short short8;
typedef __attribute__((ext_vector_type(8))) unsigned short ushort8;
typedef __attribute__((ext_vector_type(4))) float f32x4;

__device__ inline float b2f(unsigned short u) {
  union { unsigned int i; float f; } c;
  c.i = ((unsigned int)u) << 16;
  return c.f;
}
__device__ inline unsigned short f2bu(float v) {
  __hip_bfloat16 h = __float2bfloat16(v);
  return *(unsigned short*)&h;
}

// ---------------- CSR build ----------------

__global__ void count_k(const int* __restrict__ dst, int E, int* __restrict__ cnt) {
  int i = blockIdx.x * blockDim.x + threadIdx.x;
  if (i < E) atomicAdd(&cnt[dst[i]], 1);
}

// single-block scan, 10 elements per thread, wave-shfl based (2 barriers).
__global__ void __launch_bounds__(1024) scan2_k(const int* __restrict__ cnt,
                                                int* __restrict__ rowptr,
                                                int* __restrict__ nxt, int n) {
  __shared__ int wsum[17];
  const int t = threadIdx.x;
  const int lane = t & 63, wv = t >> 6;  // 16 waves
  const int base = t * 10;
  int local[10];
  int sum = 0;
#pragma unroll
  for (int i = 0; i < 10; ++i) {
    int v = (base + i < n) ? cnt[base + i] : 0;
    local[i] = sum;
    sum += v;
  }
  int incl = sum;
#pragma unroll
  for (int off = 1; off < 64; off <<= 1) {
    int u = __shfl_up(incl, off, 64);
    if (lane >= off) incl += u;
  }
  if (lane == 63) wsum[wv] = incl;
  __syncthreads();
  if (wv == 0) {
    int v = (lane < 16) ? wsum[lane] : 0;
    int winc = v;
#pragma unroll
    for (int off = 1; off < 16; off <<= 1) {
      int u = __shfl_up(winc, off, 64);
      if (lane >= off) winc += u;
    }
    if (lane < 16) wsum[lane] = winc - v;  // exclusive wave offset
    if (lane == 15) wsum[16] = winc;       // grand total
  }
  __syncthreads();
  const int off0 = wsum[wv] + incl - sum;
#pragma unroll
  for (int i = 0; i < 10; ++i) {
    if (base + i < n) {
      const int e = off0 + local[i];
      rowptr[base + i] = e;
      nxt[base + i] = e;
    }
  }
  if (t == 0) rowptr[n] = wsum[16];
}

__global__ void fill_k(const int* __restrict__ src, const int* __restrict__ dst,
                       int E, int* __restrict__ nxt, int* __restrict__ csr_src) {
  int i = blockIdx.x * blockDim.x + threadIdx.x;
  if (i < E) {
    int pos = atomicAdd(&nxt[dst[i]], 1);
    csr_src[pos] = src[i];
  }
}

// ---------------- conversions (7 jobs in one launch) ----------------
// jobs 0..5: W [K][O] f32 -> Wt [O][K] bf16 transpose.  job 6: x f32 -> bf16.
struct CvArgs {
  const float* src[7];
  unsigned short* dst[7];
  int K[7];
  int O[7];  // job 6: K=0 flag, O = total elems
};

__global__ void conv_k(CvArgs a) {
  const int m = blockIdx.y;
  const float* s = a.src[m];
  unsigned short* d = a.dst[m];
  const int K = a.K[m];
  if (K == 0) {  // straight convert
    const int n = a.O[m];
    for (int idx = blockIdx.x * 256 + threadIdx.x; idx < n; idx += gridDim.x * 256)
      d[idx] = f2bu(s[idx]);
  } else {
    const int O = a.O[m], n = K * O;
    for (int idx = blockIdx.x * 256 + threadIdx.x; idx < n; idx += gridDim.x * 256) {
      const int col = idx / K, k = idx - col * K;  // dst [col][k]
      d[idx] = f2bu(s[k * O + col]);
    }
  }
}

// ---------------- bf16 MFMA GEMM: Y[M,O] = Xb[M,K] @ Wt[O,K]^T, bf16 out ----

template <int K, int O>
__global__ void __launch_bounds__(256) mfma_gemm_k(
    const unsigned short* __restrict__ Xb, const unsigned short* __restrict__ WtL,
    const unsigned short* __restrict__ WtR, unsigned short* __restrict__ xlb,
    unsigned short* __restrict__ xrb) {
  const int wv = threadIdx.x >> 6, lane = threadIdx.x & 63;
  const int rowBase = blockIdx.x * 64 + wv * 16;
  const int colBase = blockIdx.y * 64;
  const unsigned short* __restrict__ Wt = blockIdx.z ? WtR : WtL;
  unsigned short* __restrict__ Y = blockIdx.z ? xrb : xlb;
  const int lr = lane & 15, lh = lane >> 4;

  int arow = rowBase + lr;
  if (arow >= N_NODES) arow = 0;  // clamp (loads only; stores guarded)
  const unsigned short* __restrict__ aptr = Xb + (size_t)arow * K + lh * 8;
  const unsigned short* __restrict__ bptr = Wt + (size_t)(colBase + lr) * K + lh * 8;

  f32x4 acc[4] = {f32x4{0,0,0,0}, f32x4{0,0,0,0}, f32x4{0,0,0,0}, f32x4{0,0,0,0}};
#pragma unroll
  for (int kt = 0; kt < K; kt += 32) {
    const short8 a = *(const short8*)(aptr + kt);
#pragma unroll
    for (int c = 0; c < 4; ++c) {
      const short8 b = *(const short8*)(bptr + (size_t)c * 16 * K + kt);
      acc[c] = __builtin_amdgcn_mfma_f32_16x16x32_bf16(a, b, acc[c], 0, 0, 0);
    }
  }
#pragma unroll
  for (int c = 0; c < 4; ++c) {
#pragma unroll
    for (int q = 0; q < 4; ++q) {
      const int r = rowBase + lh * 4 + q;
      if (r < N_NODES) Y[(size_t)r * O + colBase + c * 16 + lr] = f2bu(acc[c][q]);
    }
  }
}

// ---------------- per-dst-node online-softmax aggregation v6 ----------------
// 1 node per 256-thread block; 4 waves = 4 quarter edge-lists (serial depth
// ~deg/16 groups). lane = (e_sub in [0,4) | cl in [0,16)); channels
// contiguous per lane; bf16 gathers with one-time xf[] conversion. 3-slot
// row ring (rows issued 3 groups ahead, idx 6 ahead); clamped over-run
// (invalid -> -inf -> w=0). 4-way (m,s,acc) merge via LDS, wave 0 reduces.
// score: p = 0.6*sum(a*t) + 0.4*sum(a*|t|)  [leaky_relu fold].

template <int O, bool FINAL>
__global__ void __launch_bounds__(256, 4) agg6_k(
    const unsigned short* __restrict__ xlb, const unsigned short* __restrict__ xrb,
    const float* __restrict__ att, const float* __restrict__ bias,
    const int* __restrict__ rowptr, const int* __restrict__ csr_src,
    void* __restrict__ outp) {
  constexpr int NCH = O / 16;
  __shared__ float sm[4], ss[4], sacc[4][O];
  const int tid = threadIdx.x;
  const int wv = tid >> 6;
  const int lane = tid & 63;
  const int node = blockIdx.x;
  const int e_sub = lane & 3;
  const int cl = lane >> 2;
  const int ch0 = cl * NCH;

  float av[NCH], xrv[NCH], acc[NCH];
#pragma unroll
  for (int k = 0; k < NCH; ++k) {
    av[k] = att[ch0 + k];
    xrv[k] = b2f(xrb[(size_t)node * O + ch0 + k]);
    acc[k] = 0.f;
  }
  const int beg = rowptr[node];
  const int end = rowptr[node + 1];
  const int deg = end - beg;
  const int qbase = deg >> 2, qrem = deg & 3;
  const int b = beg + wv * qbase + min(wv, qrem);
  const int e_end = b + qbase + (wv < qrem ? 1 : 0);

  float m = -INFINITY, s = 0.f;
  if (b < e_end) {
    const int e_last = e_end - 1;
    const int G = (e_end - b + 3) >> 2;
    const int G3 = ((G + 2) / 3) * 3;
    auto idx_of = [&](int g) -> int {
      int ei = b + 4 * g + e_sub;
      return csr_src[ei < e_last ? ei : e_last];
    };
    ushort8 lo0, hi0, lo1, hi1, lo2, hi2;
    {
      const int i0 = idx_of(0), i1 = idx_of(1), i2 = idx_of(2);
      const ushort8* r0 = (const ushort8*)(xlb + (size_t)i0 * O + ch0);
      const ushort8* r1 = (const ushort8*)(xlb + (size_t)i1 * O + ch0);
      const ushort8* r2 = (const ushort8*)(xlb + (size_t)i2 * O + ch0);
      lo0 = r0[0]; lo1 = r1[0]; lo2 = r2[0];
      if constexpr (NCH == 16) { hi0 = r0[1]; hi1 = r1[1]; hi2 = r2[1]; }
    }
    int jA = idx_of(3), jB = idx_of(4), jC = idx_of(5);

    auto step = [&](ushort8& lo, ushort8& hi, int& jref, int g, int gref) {
      float xf[NCH];
#pragma unroll
      for (int k = 0; k < 8; ++k) xf[k] = b2f(lo[k]);
      if constexpr (NCH == 16) {
#pragma unroll
        for (int k = 0; k < 8; ++k) xf[8 + k] = b2f(hi[k]);
      }
      float p1 = 0.f, p2 = 0.f;
#pragma unroll
      for (int k = 0; k < NCH; ++k) {
        const float t = xf[k] + xrv[k];
        p1 = fmaf(av[k], t, p1);
        p2 = fmaf(av[k], fabsf(t), p2);
      }
      float p = fmaf(0.6f, p1, 0.4f * p2);
      if (b + 4 * g + e_sub >= e_end) p = -INFINITY;
      p += __shfl_xor(p, 4, 64);
      p += __shfl_xor(p, 8, 64);
      p += __shfl_xor(p, 16, 64);
      p += __shfl_xor(p, 32, 64);
      float q = fmaxf(p, __shfl_xor(p, 1, 64));
      q = fmaxf(q, __shfl_xor(q, 2, 64));
      const float m_new = fmaxf(m, q);
      const float w = __expf(p - m_new);  // 0 for invalid
      float ws = w + __shfl_xor(w, 1, 64);
      ws += __shfl_xor(ws, 2, 64);
      if (m_new > m) {  // wave-uniform
        const float f = __expf(m - m_new);
        s *= f;
#pragma unroll
        for (int k = 0; k < NCH; ++k) acc[k] *= f;
        m = m_new;
      }
      s += ws;
#pragma unroll
      for (int k = 0; k < NCH; ++k) acc[k] = fmaf(w, xf[k], acc[k]);
      // reissue rows for g+3 into this slot, idx for g+6
      const ushort8* rp = (const ushort8*)(xlb + (size_t)jref * O + ch0);
      lo = rp[0];
      if constexpr (NCH == 16) hi = rp[1];
      jref = idx_of(gref);
    };

    for (int g = 0; g < G3; g += 3) {
      step(lo0, hi0, jA, g, g + 6);
      step(lo1, hi1, jB, g + 1, g + 7);
      step(lo2, hi2, jC, g + 2, g + 8);
    }
  }
  // collapse 4 edge-residue copies within the wave
#pragma unroll
  for (int k = 0; k < NCH; ++k) {
    acc[k] += __shfl_xor(acc[k], 1, 64);
    acc[k] += __shfl_xor(acc[k], 2, 64);
  }
  // all waves publish
  if (lane == 0) { sm[wv] = m; ss[wv] = s; }
  if (e_sub == 0) {
#pragma unroll
    for (int k = 0; k < NCH; ++k) sacc[wv][ch0 + k] = acc[k];
  }
  __syncthreads();
  // wave 0 merges 4 quarters and writes output
  if (wv == 0) {
    const float m0 = sm[0], m1 = sm[1], m2 = sm[2], m3 = sm[3];
    const float mt = fmaxf(fmaxf(m0, m1), fmaxf(m2, m3));
    const float f0 = __expf(m0 - mt), f1 = __expf(m1 - mt);
    const float f2 = __expf(m2 - mt), f3 = __expf(m3 - mt);
    const float st = ss[0] * f0 + ss[1] * f1 + ss[2] * f2 + ss[3] * f3;
    const float inv = 1.f / (st + 1e-16f);
#pragma unroll
    for (int c = 0; c < O / 64; ++c) {
      const int ch = c * 64 + lane;
      float v = (sacc[0][ch] * f0 + sacc[1][ch] * f1 + sacc[2][ch] * f2 + sacc[3][ch] * f3) * inv +
                bias[ch];
      v = (v > 0.f) ? v : 0.f;  // relu
      if (FINAL) {
        ((float*)outp)[(size_t)node * O + ch] = 1.f / (1.f + __expf(-v));
      } else {
        ((unsigned short*)outp)[(size_t)node * O + ch] = f2bu(v);
      }
    }
  }
}

// ---------------- launch ----------------

extern "C" void kernel_launch(void* const* d_in, const int* in_sizes, int n_in,
                              void* d_out, int out_size, void* d_ws, size_t ws_size,
                              hipStream_t stream) {
  const float* x = (const float*)d_in[0];
  const int* ei = (const int*)d_in[1];
  const int E = in_sizes[1] / 2;
  const int* src = ei;
  const int* dst = ei + E;
  const float* Wl[3] = {(const float*)d_in[2], (const float*)d_in[6], (const float*)d_in[10]};
  const float* Wr[3] = {(const float*)d_in[3], (const float*)d_in[7], (const float*)d_in[11]};
  const float* att[3] = {(const float*)d_in[4], (const float*)d_in[8], (const float*)d_in[12]};
  const float* bia[3] = {(const float*)d_in[5], (const float*)d_in[9], (const float*)d_in[13]};

  char* ws = (char*)d_ws;
  size_t off = 0;
  auto alloc = [&](size_t bytes) -> void* {
    void* p = ws + off;
    off = (off + bytes + 255) & ~(size_t)255;
    return p;
  };
  int* cnt = (int*)alloc((size_t)N_NODES * sizeof(int));
  int* rowptr = (int*)alloc((size_t)(N_NODES + 1) * sizeof(int));
  int* nxt = (int*)alloc((size_t)N_NODES * sizeof(int));
  int* csr_src = (int*)alloc((size_t)E * sizeof(int));
  unsigned short* xlb = (unsigned short*)alloc((size_t)N_NODES * 256 * 2);
  unsigned short* xrb = (unsigned short*)alloc((size_t)N_NODES * 256 * 2);
  unsigned short* xb = (unsigned short*)alloc((size_t)N_NODES * 128 * 2);
  unsigned short* curb = (unsigned short*)alloc((size_t)N_NODES * 256 * 2);
  unsigned short* wt[6];
  const int wk[6] = {128, 128, 256, 256, 256, 256};
  const int wo[6] = {256, 256, 256, 256, 128, 128};
  for (int i = 0; i < 6; ++i) wt[i] = (unsigned short*)alloc((size_t)wk[i] * wo[i] * 2);

  hipMemsetAsync(cnt, 0, (size_t)N_NODES * sizeof(int), stream);

  // ---- CSR by dst (stateless) ----
  count_k<<<(E + 255) / 256, 256, 0, stream>>>(dst, E, cnt);
  scan2_k<<<1, 1024, 0, stream>>>(cnt, rowptr, nxt, N_NODES);
  fill_k<<<(E + 255) / 256, 256, 0, stream>>>(src, dst, E, nxt, csr_src);

  // ---- conversions: 6 W transposes + x convert, one launch ----
  CvArgs ca;
  const float* wsrc[6] = {Wl[0], Wr[0], Wl[1], Wr[1], Wl[2], Wr[2]};
  for (int i = 0; i < 6; ++i) { ca.src[i] = wsrc[i]; ca.dst[i] = wt[i]; ca.K[i] = wk[i]; ca.O[i] = wo[i]; }
  ca.src[6] = x; ca.dst[6] = xb; ca.K[6] = 0; ca.O[6] = N_NODES * 128;
  conv_k<<<dim3(80, 7), 256, 0, stream>>>(ca);

  // ---- layer 0: 128 -> 256 ----
  mfma_gemm_k<128, 256><<<dim3(157, 4, 2), 256, 0, stream>>>(xb, wt[0], wt[1], xlb, xrb);
  agg6_k<256, false><<<N_NODES, 256, 0, stream>>>(xlb, xrb, att[0], bia[0], rowptr, csr_src, curb);

  // ---- layer 1: 256 -> 256 ----
  mfma_gemm_k<256, 256><<<dim3(157, 4, 2), 256, 0, stream>>>(curb, wt[2], wt[3], xlb, xrb);
  agg6_k<256, false><<<N_NODES, 256, 0, stream>>>(xlb, xrb, att[1], bia[1], rowptr, csr_src, curb);

  // ---- layer 2: 256 -> 128 ----
  mfma_gemm_k<256, 128><<<dim3(157, 2, 2), 256, 0, stream>>>(curb, wt[4], wt[5], xlb, xrb);
  agg6_k<128, true><<<N_NODES, 256, 0, stream>>>(xlb, xrb, att[2], bia[2], rowptr, csr_src, d_out);
}

// Round 7
// 281.347 us; speedup vs baseline: 1.2570x; 1.2570x over previous
//
#include <hip/hip_runtime.h>
#include <hip/hip_bf16.h>
#include <math.h>

#define N_NODES 10000

typedef __attribute__((ext_vector_type(8))) short short8;
typedef __attribute__((ext_vector_type(8))) unsigned short ushort8;
typedef __attribute__((ext_vector_type(4))) float f32x4;

__device__ inline float b2f(unsigned short u) {
  union { unsigned int i; float f; } c;
  c.i = ((unsigned int)u) << 16;
  return c.f;
}
__device__ inline unsigned short f2bu(float v) {
  __hip_bfloat16 h = __float2bfloat16(v);
  return *(unsigned short*)&h;
}

// row_ror DPP add: x += rotate-within-row-of-16(x, CTRL). Pure VALU.
template <int CTRL>
__device__ inline float dpp_radd(float x) {
  union { float f; int i; } u, v;
  u.f = x;
  v.i = __builtin_amdgcn_update_dpp(0, u.i, CTRL, 0xf, 0xf, true);
  return x + v.f;
}

// ---------------- CSR build ----------------

__global__ void count_k(const int* __restrict__ dst, int E, int* __restrict__ cnt) {
  int i = blockIdx.x * blockDim.x + threadIdx.x;
  if (i < E) atomicAdd(&cnt[dst[i]], 1);
}

// single-block scan, 10 elements per thread, wave-shfl based (2 barriers).
__global__ void __launch_bounds__(1024) scan2_k(const int* __restrict__ cnt,
                                                int* __restrict__ rowptr,
                                                int* __restrict__ nxt, int n) {
  __shared__ int wsum[17];
  const int t = threadIdx.x;
  const int lane = t & 63, wv = t >> 6;  // 16 waves
  const int base = t * 10;
  int local[10];
  int sum = 0;
#pragma unroll
  for (int i = 0; i < 10; ++i) {
    int v = (base + i < n) ? cnt[base + i] : 0;
    local[i] = sum;
    sum += v;
  }
  int incl = sum;
#pragma unroll
  for (int off = 1; off < 64; off <<= 1) {
    int u = __shfl_up(incl, off, 64);
    if (lane >= off) incl += u;
  }
  if (lane == 63) wsum[wv] = incl;
  __syncthreads();
  if (wv == 0) {
    int v = (lane < 16) ? wsum[lane] : 0;
    int winc = v;
#pragma unroll
    for (int off = 1; off < 16; off <<= 1) {
      int u = __shfl_up(winc, off, 64);
      if (lane >= off) winc += u;
    }
    if (lane < 16) wsum[lane] = winc - v;  // exclusive wave offset
    if (lane == 15) wsum[16] = winc;       // grand total
  }
  __syncthreads();
  const int off0 = wsum[wv] + incl - sum;
#pragma unroll
  for (int i = 0; i < 10; ++i) {
    if (base + i < n) {
      const int e = off0 + local[i];
      rowptr[base + i] = e;
      nxt[base + i] = e;
    }
  }
  if (t == 0) rowptr[n] = wsum[16];
}

__global__ void fill_k(const int* __restrict__ src, const int* __restrict__ dst,
                       int E, int* __restrict__ nxt, int* __restrict__ csr_src) {
  int i = blockIdx.x * blockDim.x + threadIdx.x;
  if (i < E) {
    int pos = atomicAdd(&nxt[dst[i]], 1);
    csr_src[pos] = src[i];
  }
}

// ---------------- conversions (7 jobs in one launch) ----------------
struct CvArgs {
  const float* src[7];
  unsigned short* dst[7];
  int K[7];
  int O[7];  // job 6: K=0 flag, O = total elems
};

__global__ void conv_k(CvArgs a) {
  const int m = blockIdx.y;
  const float* s = a.src[m];
  unsigned short* d = a.dst[m];
  const int K = a.K[m];
  if (K == 0) {  // straight convert
    const int n = a.O[m];
    for (int idx = blockIdx.x * 256 + threadIdx.x; idx < n; idx += gridDim.x * 256)
      d[idx] = f2bu(s[idx]);
  } else {
    const int O = a.O[m], n = K * O;
    for (int idx = blockIdx.x * 256 + threadIdx.x; idx < n; idx += gridDim.x * 256) {
      const int col = idx / K, k = idx - col * K;  // dst [col][k]
      d[idx] = f2bu(s[k * O + col]);
    }
  }
}

// ---------------- bf16 MFMA GEMM: Y[M,O] = Xb[M,K] @ Wt[O,K]^T, bf16 out ----

template <int K, int O>
__global__ void __launch_bounds__(256) mfma_gemm_k(
    const unsigned short* __restrict__ Xb, const unsigned short* __restrict__ WtL,
    const unsigned short* __restrict__ WtR, unsigned short* __restrict__ xlb,
    unsigned short* __restrict__ xrb) {
  const int wv = threadIdx.x >> 6, lane = threadIdx.x & 63;
  const int rowBase = blockIdx.x * 64 + wv * 16;
  const int colBase = blockIdx.y * 64;
  const unsigned short* __restrict__ Wt = blockIdx.z ? WtR : WtL;
  unsigned short* __restrict__ Y = blockIdx.z ? xrb : xlb;
  const int lr = lane & 15, lh = lane >> 4;

  int arow = rowBase + lr;
  if (arow >= N_NODES) arow = 0;  // clamp (loads only; stores guarded)
  const unsigned short* __restrict__ aptr = Xb + (size_t)arow * K + lh * 8;
  const unsigned short* __restrict__ bptr = Wt + (size_t)(colBase + lr) * K + lh * 8;

  f32x4 acc[4] = {f32x4{0,0,0,0}, f32x4{0,0,0,0}, f32x4{0,0,0,0}, f32x4{0,0,0,0}};
#pragma unroll
  for (int kt = 0; kt < K; kt += 32) {
    const short8 a = *(const short8*)(aptr + kt);
#pragma unroll
    for (int c = 0; c < 4; ++c) {
      const short8 b = *(const short8*)(bptr + (size_t)c * 16 * K + kt);
      acc[c] = __builtin_amdgcn_mfma_f32_16x16x32_bf16(a, b, acc[c], 0, 0, 0);
    }
  }
#pragma unroll
  for (int c = 0; c < 4; ++c) {
#pragma unroll
    for (int q = 0; q < 4; ++q) {
      const int r = rowBase + lh * 4 + q;
      if (r < N_NODES) Y[(size_t)r * O + colBase + c * 16 + lr] = f2bu(acc[c][q]);
    }
  }
}

// ---------------- per-dst-node online-softmax aggregation v7 ----------------
// 2 nodes/block x 2 half-lists (R4 structure). NEW lane map: cl = lane&15
// (channel group, LOW bits), e_sub = lane>>4 (edge residue, HIGH bits).
// Score row-sum = 4x v_add_f32 DPP row_ror {1,2,4,8} -- zero DS ops.
// Defer-max (THR=8): rescale branch (cross-row shuffles) only when a new
// max exceeds m+8. Per-lane s accumulation; s/acc collapsed ^16/^32 once at
// wave end. 3-slot row ring (rows +3 groups ahead, idx +6), clamped overrun.

template <int O, bool FINAL>
__global__ void __launch_bounds__(256, 4) agg7_k(
    const unsigned short* __restrict__ xlb, const unsigned short* __restrict__ xrb,
    const float* __restrict__ att, const float* __restrict__ bias,
    const int* __restrict__ rowptr, const int* __restrict__ csr_src,
    void* __restrict__ outp) {
  constexpr int NCH = O / 16;  // 16 (O=256) or 8 (O=128)
  __shared__ float sm[2], ss[2], sacc[2][O];
  const int tid = threadIdx.x;
  const int wv = tid >> 6;
  const int lane = tid & 63;
  const int nloc = wv >> 1;  // node within block
  const int half = wv & 1;   // half of edge list
  const int node = blockIdx.x * 2 + nloc;
  const int cl = lane & 15;   // channel group (low bits -> DPP row = edge)
  const int e_sub = lane >> 4;
  const int ch0 = cl * NCH;

  float av[NCH], xrv[NCH], acc[NCH];
#pragma unroll
  for (int k = 0; k < NCH; ++k) {
    av[k] = att[ch0 + k];
    xrv[k] = b2f(xrb[(size_t)node * O + ch0 + k]);
    acc[k] = 0.f;
  }
  const int beg = rowptr[node];
  const int end = rowptr[node + 1];
  const int h0 = (end - beg + 1) >> 1;
  const int b = half ? beg + h0 : beg;
  const int e_end = half ? end : beg + h0;

  float m = -INFINITY, s = 0.f;
  if (b < e_end) {
    const int e_last = e_end - 1;
    const int G = (e_end - b + 3) >> 2;
    const int G3 = ((G + 2) / 3) * 3;
    auto idx_of = [&](int g) -> int {
      int ei = b + 4 * g + e_sub;
      return csr_src[ei < e_last ? ei : e_last];
    };
    ushort8 lo0, hi0, lo1, hi1, lo2, hi2;
    {
      const int i0 = idx_of(0), i1 = idx_of(1), i2 = idx_of(2);
      const ushort8* r0 = (const ushort8*)(xlb + (size_t)i0 * O + ch0);
      const ushort8* r1 = (const ushort8*)(xlb + (size_t)i1 * O + ch0);
      const ushort8* r2 = (const ushort8*)(xlb + (size_t)i2 * O + ch0);
      lo0 = r0[0]; lo1 = r1[0]; lo2 = r2[0];
      if constexpr (NCH == 16) { hi0 = r0[1]; hi1 = r1[1]; hi2 = r2[1]; }
    }
    int jA = idx_of(3), jB = idx_of(4), jC = idx_of(5);

    auto step = [&](ushort8& lo, ushort8& hi, int& jref, int g, int gref) {
      float xf[NCH];
#pragma unroll
      for (int k = 0; k < 8; ++k) xf[k] = b2f(lo[k]);
      if constexpr (NCH == 16) {
#pragma unroll
        for (int k = 0; k < 8; ++k) xf[8 + k] = b2f(hi[k]);
      }
      // score partials (2-way split to shorten fma chains)
      float p1a = 0.f, p1b = 0.f, p2a = 0.f, p2b = 0.f;
#pragma unroll
      for (int k = 0; k < NCH; k += 2) {
        const float ta = xf[k] + xrv[k];
        const float tb = xf[k + 1] + xrv[k + 1];
        p1a = fmaf(av[k], ta, p1a);
        p2a = fmaf(av[k], fabsf(ta), p2a);
        p1b = fmaf(av[k + 1], tb, p1b);
        p2b = fmaf(av[k + 1], fabsf(tb), p2b);
      }
      float p = fmaf(0.6f, p1a + p1b, 0.4f * (p2a + p2b));
      if (b + 4 * g + e_sub >= e_end) p = -INFINITY;  // invalid edge-row
      // 16-lane row sum, pure VALU (DPP row_ror 1,2,4,8)
      p = dpp_radd<0x121>(p);
      p = dpp_radd<0x122>(p);
      p = dpp_radd<0x124>(p);
      p = dpp_radd<0x128>(p);
      // defer-max: rescale only when new max exceeds m+8
      if (!__all(p <= m + 8.f)) {
        float q = fmaxf(p, __shfl_xor(p, 16, 64));
        q = fmaxf(q, __shfl_xor(q, 32, 64));  // wave max (uniform)
        const float f = __expf(m - q);        // exp(-inf)=0 on first group
        s *= f;
#pragma unroll
        for (int k = 0; k < NCH; ++k) acc[k] *= f;
        m = q;
      }
      const float w = __expf(p - m);  // 0 for invalid rows; <= e^8 bounded
      s += w;
#pragma unroll
      for (int k = 0; k < NCH; ++k) acc[k] = fmaf(w, xf[k], acc[k]);
      // reissue rows for g+3 into this slot, idx for g+6
      const ushort8* rp = (const ushort8*)(xlb + (size_t)jref * O + ch0);
      lo = rp[0];
      if constexpr (NCH == 16) hi = rp[1];
      jref = idx_of(gref);
    };

    for (int g = 0; g < G3; g += 3) {
      step(lo0, hi0, jA, g, g + 6);
      step(lo1, hi1, jB, g + 1, g + 7);
      step(lo2, hi2, jC, g + 2, g + 8);
    }
  }
  // cross-row collapse (once per wave): each lane ends with wave totals
  s += __shfl_xor(s, 16, 64);
  s += __shfl_xor(s, 32, 64);
#pragma unroll
  for (int k = 0; k < NCH; ++k) {
    acc[k] += __shfl_xor(acc[k], 16, 64);
    acc[k] += __shfl_xor(acc[k], 32, 64);
  }
  if (half == 1) {
    if (lane == 0) { sm[nloc] = m; ss[nloc] = s; }
    if (lane < 16) {
#pragma unroll
      for (int k = 0; k < NCH; ++k) sacc[nloc][ch0 + k] = acc[k];
    }
  }
  __syncthreads();
  if (half == 0 && lane < 16) {
    const float m1 = sm[nloc], s1 = ss[nloc];
    const float mt = fmaxf(m, m1);
    const float f0 = __expf(m - mt);
    const float f1 = __expf(m1 - mt);  // 0 if other half empty
    const float st = s * f0 + s1 * f1;
    const float inv = 1.f / (st + 1e-16f);
    float vo[NCH];
#pragma unroll
    for (int k = 0; k < NCH; ++k) {
      float v = (acc[k] * f0 + sacc[nloc][ch0 + k] * f1) * inv + bias[ch0 + k];
      v = (v > 0.f) ? v : 0.f;  // relu
      if (FINAL) v = 1.f / (1.f + __expf(-v));  // sigmoid
      vo[k] = v;
    }
    if (FINAL) {
      float* op = (float*)outp + (size_t)node * O + ch0;
#pragma unroll
      for (int k = 0; k < NCH; k += 4)
        *(float4*)(op + k) = make_float4(vo[k], vo[k + 1], vo[k + 2], vo[k + 3]);
    } else {
      unsigned short* op = (unsigned short*)outp + (size_t)node * O + ch0;
#pragma unroll
      for (int v8 = 0; v8 < NCH / 8; ++v8) {
        ushort8 o;
#pragma unroll
        for (int k = 0; k < 8; ++k) o[k] = f2bu(vo[v8 * 8 + k]);
        *(ushort8*)(op + v8 * 8) = o;
      }
    }
  }
}

// ---------------- launch ----------------

extern "C" void kernel_launch(void* const* d_in, const int* in_sizes, int n_in,
                              void* d_out, int out_size, void* d_ws, size_t ws_size,
                              hipStream_t stream) {
  const float* x = (const float*)d_in[0];
  const int* ei = (const int*)d_in[1];
  const int E = in_sizes[1] / 2;
  const int* src = ei;
  const int* dst = ei + E;
  const float* Wl[3] = {(const float*)d_in[2], (const float*)d_in[6], (const float*)d_in[10]};
  const float* Wr[3] = {(const float*)d_in[3], (const float*)d_in[7], (const float*)d_in[11]};
  const float* att[3] = {(const float*)d_in[4], (const float*)d_in[8], (const float*)d_in[12]};
  const float* bia[3] = {(const float*)d_in[5], (const float*)d_in[9], (const float*)d_in[13]};

  char* ws = (char*)d_ws;
  size_t off = 0;
  auto alloc = [&](size_t bytes) -> void* {
    void* p = ws + off;
    off = (off + bytes + 255) & ~(size_t)255;
    return p;
  };
  int* cnt = (int*)alloc((size_t)N_NODES * sizeof(int));
  int* rowptr = (int*)alloc((size_t)(N_NODES + 1) * sizeof(int));
  int* nxt = (int*)alloc((size_t)N_NODES * sizeof(int));
  int* csr_src = (int*)alloc((size_t)E * sizeof(int));
  unsigned short* xlb = (unsigned short*)alloc((size_t)N_NODES * 256 * 2);
  unsigned short* xrb = (unsigned short*)alloc((size_t)N_NODES * 256 * 2);
  unsigned short* xb = (unsigned short*)alloc((size_t)N_NODES * 128 * 2);
  unsigned short* curb = (unsigned short*)alloc((size_t)N_NODES * 256 * 2);
  unsigned short* wt[6];
  const int wk[6] = {128, 128, 256, 256, 256, 256};
  const int wo[6] = {256, 256, 256, 256, 128, 128};
  for (int i = 0; i < 6; ++i) wt[i] = (unsigned short*)alloc((size_t)wk[i] * wo[i] * 2);

  hipMemsetAsync(cnt, 0, (size_t)N_NODES * sizeof(int), stream);

  // ---- CSR by dst (stateless) ----
  count_k<<<(E + 255) / 256, 256, 0, stream>>>(dst, E, cnt);
  scan2_k<<<1, 1024, 0, stream>>>(cnt, rowptr, nxt, N_NODES);
  fill_k<<<(E + 255) / 256, 256, 0, stream>>>(src, dst, E, nxt, csr_src);

  // ---- conversions: 6 W transposes + x convert, one launch ----
  CvArgs ca;
  const float* wsrc[6] = {Wl[0], Wr[0], Wl[1], Wr[1], Wl[2], Wr[2]};
  for (int i = 0; i < 6; ++i) { ca.src[i] = wsrc[i]; ca.dst[i] = wt[i]; ca.K[i] = wk[i]; ca.O[i] = wo[i]; }
  ca.src[6] = x; ca.dst[6] = xb; ca.K[6] = 0; ca.O[6] = N_NODES * 128;
  conv_k<<<dim3(80, 7), 256, 0, stream>>>(ca);

  // ---- layer 0: 128 -> 256 ----
  mfma_gemm_k<128, 256><<<dim3(157, 4, 2), 256, 0, stream>>>(xb, wt[0], wt[1], xlb, xrb);
  agg7_k<256, false><<<N_NODES / 2, 256, 0, stream>>>(xlb, xrb, att[0], bia[0], rowptr, csr_src, curb);

  // ---- layer 1: 256 -> 256 ----
  mfma_gemm_k<256, 256><<<dim3(157, 4, 2), 256, 0, stream>>>(curb, wt[2], wt[3], xlb, xrb);
  agg7_k<256, false><<<N_NODES / 2, 256, 0, stream>>>(xlb, xrb, att[1], bia[1], rowptr, csr_src, curb);

  // ---- layer 2: 256 -> 128 ----
  mfma_gemm_k<256, 128><<<dim3(157, 2, 2), 256, 0, stream>>>(curb, wt[4], wt[5], xlb, xrb);
  agg7_k<128, true><<<N_NODES / 2, 256, 0, stream>>>(xlb, xrb, att[2], bia[2], rowptr, csr_src, d_out);
}